// Round 11
// baseline (192.714 us; speedup 1.0000x reference)
//
#include <hip/hip_runtime.h>

#define Bq 8
#define Tq 64
#define Sq 256
#define Hq 768
#define GPB 16          // workgroups per batch (scan)
#define NSTEP 64

typedef float f32x4 __attribute__((ext_vector_type(4)));
typedef __bf16 bf16x8 __attribute__((ext_vector_type(8)));

#define TANH_SCALE 2.885390081777927f   // 2*log2(e)
#define INV_TS     0.34657359027997264f // 1/TANH_SCALE
#define LOG2E 1.4426950408889634f
#define POISON 0xFFFFFFFFu
#define ZMASK 0xFFFFFFFFFFFFFULL        // low 52 bits: fixed-point Z sum
#define SPEC_THR 0.0625f                // Taylor guard (wave-uniform)

// ---- DPP reduction helpers (VALU-pipe; ctrl/rmask must be literal consts) ---
template <int Ctrl, int Rmask>
__device__ __forceinline__ float dpp_add_f(float v) {
  int t = __builtin_amdgcn_update_dpp(0, __float_as_int(v), Ctrl, Rmask, 0xF, true);
  return v + __int_as_float(t);
}
// full 64-lane sum, result broadcast to all lanes via readlane(63)
__device__ __forceinline__ float wave64_sum(float v) {
  v = dpp_add_f<0xB1, 0xF>(v);    // xor1
  v = dpp_add_f<0x4E, 0xF>(v);    // xor2
  v = dpp_add_f<0x141, 0xF>(v);   // xor4
  v = dpp_add_f<0x140, 0xF>(v);   // xor8
  v = dpp_add_f<0x142, 0xA>(v);   // row_bcast15
  v = dpp_add_f<0x143, 0xC>(v);   // row_bcast31 ; lane63 = total
  return __int_as_float(__builtin_amdgcn_readlane(__float_as_int(v), 63));
}
// sum within each 16-lane row (rows replicate 16 values -> every lane = total)
__device__ __forceinline__ float row16_sum(float v) {
  v = dpp_add_f<0xB1, 0xF>(v);
  v = dpp_add_f<0x4E, 0xF>(v);
  v = dpp_add_f<0x141, 0xF>(v);
  v = dpp_add_f<0x140, 0xF>(v);
  return v;
}

// ---------------- projection GEMMs (bf16 MFMA, direct-from-global frags) -----
// XCD-affinity remap: round-robin dispatch puts all n-tiles of one A m-panel
// on the same XCD (bm = bid mod 32 / mod 8) -> A/W re-reads are L2-local.
// Side duty: zero the Zsync words + loss accumulator.
__global__ __launch_bounds__(256) void proj_kernel(
    const float* __restrict__ enc, const float* __restrict__ dec,
    const float* __restrict__ Wh, const float* __restrict__ Wd,
    const float* __restrict__ bd,
    float* __restrict__ ef, float* __restrict__ decf,
    unsigned long long* __restrict__ Zsync, float* __restrict__ lacc)
{
  {
    int idx = blockIdx.x * 256 + threadIdx.x;
    if (idx < Bq * NSTEP * 8) Zsync[idx] = 0ULL;   // 64B stride per (b,t) word
    if (idx == 0) lacc[0] = 0.f;
  }

  int bid = blockIdx.x;
  const int efBlocks = 384;                     // 32 m-panels x 12 n-tiles
  const float* A; const float* W; float* C; bool hasBias;
  int bm, bn;
  if (bid < efBlocks) {
    A = enc; W = Wh; C = ef; hasBias = false;
    bm = bid % 32; bn = bid / 32;               // XCD = bid%8 = bm%8
  } else {
    bid -= efBlocks;
    A = dec; W = Wd; C = decf; hasBias = true;
    bm = bid % 8; bn = bid / 8;                 // XCD = bm%8
  }
  int w = threadIdx.x >> 6, ln = threadIdx.x & 63;
  int m0 = bm * 64 + (w >> 1) * 32;
  int n0 = bn * 64 + (w & 1) * 32;
  int rsel = ln & 15;
  int kof = (ln >> 4) * 8;
  f32x4 acc[2][2] = {};
  for (int k0 = 0; k0 < Hq; k0 += 32) {
    bf16x8 af[2], bfr[2];
#pragma unroll
    for (int tm = 0; tm < 2; tm++) {
      const float* p = A + (size_t)(m0 + tm * 16 + rsel) * Hq + k0 + kof;
      f32x4 lo = *(const f32x4*)p, hi = *(const f32x4*)(p + 4);
      bf16x8 t;
      t[0] = (__bf16)lo[0]; t[1] = (__bf16)lo[1]; t[2] = (__bf16)lo[2]; t[3] = (__bf16)lo[3];
      t[4] = (__bf16)hi[0]; t[5] = (__bf16)hi[1]; t[6] = (__bf16)hi[2]; t[7] = (__bf16)hi[3];
      af[tm] = t;
    }
#pragma unroll
    for (int tn = 0; tn < 2; tn++) {
      const float* p = W + (size_t)(n0 + tn * 16 + rsel) * Hq + k0 + kof;
      f32x4 lo = *(const f32x4*)p, hi = *(const f32x4*)(p + 4);
      bf16x8 t;
      t[0] = (__bf16)lo[0]; t[1] = (__bf16)lo[1]; t[2] = (__bf16)lo[2]; t[3] = (__bf16)lo[3];
      t[4] = (__bf16)hi[0]; t[5] = (__bf16)hi[1]; t[6] = (__bf16)hi[2]; t[7] = (__bf16)hi[3];
      bfr[tn] = t;
    }
#pragma unroll
    for (int tm = 0; tm < 2; tm++)
#pragma unroll
      for (int tn = 0; tn < 2; tn++)
        acc[tm][tn] = __builtin_amdgcn_mfma_f32_16x16x32_bf16(af[tm], bfr[tn], acc[tm][tn], 0, 0, 0);
  }
  int col = ln & 15, rb = (ln >> 4) * 4;
#pragma unroll
  for (int tm = 0; tm < 2; tm++)
#pragma unroll
    for (int tn = 0; tn < 2; tn++)
#pragma unroll
      for (int j = 0; j < 4; j++) {
        int r = m0 + tm * 16 + rb + j, c = n0 + tn * 16 + col;
        float val = acc[tm][tn][j];
        if (hasBias) val += bd[c];
        C[(size_t)r * Hq + c] = val * TANH_SCALE;
      }
}

// ---------------- persistent scan kernel -------------------------------------
// 128 blocks x 1024 threads (16 waves). b = bid&7, g = bid>>3. Wave w owns
// row s0 = g*16 + w (12 elems/lane).
// Speculative pipeline: while waiting for Z_t, each wave computes
//   A = sum v*tanh(u), B = sum 4*v*wc*r*(1-r)   (u uses cov_t)
// for step t+1; once Z_t arrives, acc_{t+1} = A + at0*INV_TS*B (first-order
// Taylor in the scalar at0; guard at0>SPEC_THR -> exact recompute). This
// hides the entire tanh pass + reductions under the IC sync round-trip.
__global__ __launch_bounds__(1024, 1) void scan_kernel(
    const float* __restrict__ ef, const float* __restrict__ decf,
    const float* __restrict__ emask, const float* __restrict__ cov0,
    const float* __restrict__ vvec, const float* __restrict__ wcvec,
    const float* __restrict__ dmask,
    float* __restrict__ out_attn, float* __restrict__ out_covf,
    unsigned long long* __restrict__ Zsync, float* __restrict__ lacc)
{
  __shared__ unsigned zsum[2][16];
  __shared__ unsigned zshs[NSTEP];
  __shared__ float lossb[16];
  const int b = blockIdx.x & 7;
  const int g = blockIdx.x >> 3;
  const int w = threadIdx.x >> 6;        // 0..15
  const int ln = threadIdx.x & 63;
  const int tid = threadIdx.x;
  const int s0 = g * 16 + w;
  const int hb = 4 * ln;

  if (tid < NSTEP) zshs[tid] = POISON;
  if (tid < 32) ((unsigned*)zsum)[tid] = POISON;
  __syncthreads();

  f32x4 vv[3], wcv[3], vwc4[3], ef0[3];
  const float* efr0 = ef + (size_t)(b * Sq + s0) * Hq;
#pragma unroll
  for (int jj = 0; jj < 3; jj++) {
    int o = hb + 256 * jj;
    vv[jj]  = *(const f32x4*)(vvec + o);
    f32x4 wcl = *(const f32x4*)(wcvec + o);
    wcv[jj] = wcl * TANH_SCALE;
    vwc4[jj] = vv[jj] * wcv[jj] * 4.0f;
    ef0[jj] = *(const f32x4*)(efr0 + o);
  }
  float cva = cov0[b * Sq + s0];
  const float em0 = emask[b * Sq + s0];
  const float dm = dmask[b * Tq + ln];   // lane t holds dmask[b][t]
  float lkeep = 0.f;

  const float* decb = decf + (size_t)(b * Tq) * Hq;

  // prologue: dv_0, exact E_0, post, add word 0; then preload dv_1
  f32x4 dvn[3], dvf[3];
#pragma unroll
  for (int jj = 0; jj < 3; jj++) dvn[jj] = *(const f32x4*)(decb + hb + 256 * jj);
#pragma unroll
  for (int jj = 0; jj < 3; jj++)
    dvf[jj] = *(const f32x4*)(decb + Hq + hb + 256 * jj);   // dv_1 in flight

  float E;
  {
    float acc0 = 0.f;
#pragma unroll
    for (int jj = 0; jj < 3; jj++)
#pragma unroll
      for (int e = 0; e < 4; e++) {
        float xa = ef0[jj][e] + dvn[jj][e] + cva * wcv[jj][e];
        float ta = 1.f - 2.f * __builtin_amdgcn_rcpf(1.f + __builtin_amdgcn_exp2f(xa));
        acc0 += vv[jj][e] * ta;
      }
    float tot = wave64_sum(acc0);
    E = __builtin_amdgcn_exp2f(tot * LOG2E) * em0;
  }
  __hip_atomic_store(&zsum[0][w], __float_as_uint(E),
                     __ATOMIC_RELAXED, __HIP_MEMORY_SCOPE_WORKGROUP);
  if (w == 0) {
    unsigned zu;
    do {
      zu = __hip_atomic_load(&zsum[0][ln & 15],
                             __ATOMIC_RELAXED, __HIP_MEMORY_SCOPE_WORKGROUP);
    } while (__ballot(zu == POISON));
    float p = row16_sum(__uint_as_float(zu));
    if (ln == 0) {
      unsigned long long pkt = (1ULL << 52) | (unsigned long long)(p * 1024.0f);
      atomicAdd(&Zsync[(b * NSTEP) * 8], pkt);
    }
    if (ln < 16)
      __hip_atomic_store(&zsum[0][ln], POISON,
                         __ATOMIC_RELAXED, __HIP_MEMORY_SCOPE_WORKGROUP);
  }

  for (int t = 0; t < NSTEP; t++) {
    // ---- speculative compute for step t+1 (hidden under the Z_t wait) ----
    float Ar = 0.f, Br = 0.f;
    if (t + 1 < NSTEP) {
#pragma unroll
      for (int jj = 0; jj < 3; jj++) dvn[jj] = dvf[jj];   // dv_{t+1} resident
      if (t + 2 < NSTEP) {
        const float* drn = decb + (size_t)(t + 2) * Hq;
#pragma unroll
        for (int jj = 0; jj < 3; jj++) dvf[jj] = *(const f32x4*)(drn + hb + 256 * jj);
      }
      float accA = 0.f, accB = 0.f;
#pragma unroll
      for (int jj = 0; jj < 3; jj++)
#pragma unroll
        for (int e = 0; e < 4; e++) {
          float xa = ef0[jj][e] + dvn[jj][e] + cva * wcv[jj][e];
          float r  = __builtin_amdgcn_rcpf(1.f + __builtin_amdgcn_exp2f(xa));
          float ta = 1.f - 2.f * r;
          accA += vv[jj][e] * ta;
          accB += vwc4[jj][e] * (r - r * r);
        }
      Ar = wave64_sum(accA);
      Br = wave64_sum(accB);
    }

    // ---- wait for Z_t ----
    const int widx = (b * NSTEP + t) * 8;
    float zf;
    if (w == 0) {
      const unsigned long long* Wp = &Zsync[widx];
      unsigned long long v0 = __hip_atomic_load(Wp, __ATOMIC_RELAXED, __HIP_MEMORY_SCOPE_AGENT);
      unsigned long long v1 = __hip_atomic_load(Wp, __ATOMIC_RELAXED, __HIP_MEMORY_SCOPE_AGENT);
      unsigned long long vf;
      for (;;) {
        if ((unsigned)(v0 >> 52) == GPB) { vf = v0; break; }
        v0 = __hip_atomic_load(Wp, __ATOMIC_RELAXED, __HIP_MEMORY_SCOPE_AGENT);
        if ((unsigned)(v1 >> 52) == GPB) { vf = v1; break; }
        v1 = __hip_atomic_load(Wp, __ATOMIC_RELAXED, __HIP_MEMORY_SCOPE_AGENT);
      }
      zf = (float)(vf & ZMASK) * (1.0f / 1024.0f);
      if (ln == 0)
        __hip_atomic_store(&zshs[t], __float_as_uint(zf),
                           __ATOMIC_RELAXED, __HIP_MEMORY_SCOPE_WORKGROUP);
    } else {
      unsigned u;
      do {
        u = __hip_atomic_load(&zshs[t],
                              __ATOMIC_RELAXED, __HIP_MEMORY_SCOPE_WORKGROUP);
      } while (u == POISON);
      zf = __uint_as_float(u);
    }

    // ---- consume Z_t ----
    const float invZ = __builtin_amdgcn_rcpf(zf);
    float at0 = E * invZ;
    float lterm = fminf(at0, cva);
    lkeep = (ln == t) ? lterm : lkeep;
    cva += at0;
    if (ln == 0)
      out_attn[(size_t)(b * Tq + t) * Sq + s0] = at0;

    // ---- produce & post E_{t+1} ----
    if (t + 1 < NSTEP) {
      float tot;
      if (at0 <= SPEC_THR) {
        tot = Ar + at0 * INV_TS * Br;          // first-order correction
      } else {
        // exact fallback (wave-uniform branch; cva already updated)
        float acc0 = 0.f;
#pragma unroll
        for (int jj = 0; jj < 3; jj++)
#pragma unroll
          for (int e = 0; e < 4; e++) {
            float xa = ef0[jj][e] + dvn[jj][e] + cva * wcv[jj][e];
            float ta = 1.f - 2.f * __builtin_amdgcn_rcpf(1.f + __builtin_amdgcn_exp2f(xa));
            acc0 += vv[jj][e] * ta;
          }
        tot = wave64_sum(acc0);
      }
      E = __builtin_amdgcn_exp2f(tot * LOG2E) * em0;
      const int parn = (t + 1) & 1;
      __hip_atomic_store(&zsum[parn][w], __float_as_uint(E),
                         __ATOMIC_RELAXED, __HIP_MEMORY_SCOPE_WORKGROUP);
      if (w == 0) {
        unsigned zu;
        do {
          zu = __hip_atomic_load(&zsum[parn][ln & 15],
                                 __ATOMIC_RELAXED, __HIP_MEMORY_SCOPE_WORKGROUP);
        } while (__ballot(zu == POISON));
        float p = row16_sum(__uint_as_float(zu));
        if (ln == 0) {
          unsigned long long pkt = (1ULL << 52) | (unsigned long long)(p * 1024.0f);
          atomicAdd(&Zsync[widx + 8], pkt);
        }
        if (ln < 16)
          __hip_atomic_store(&zsum[parn][ln], POISON,
                             __ATOMIC_RELAXED, __HIP_MEMORY_SCOPE_WORKGROUP);
      }
    }
  }

  float lp = wave64_sum(lkeep * dm);
  if (ln == 0) {
    out_covf[b * Sq + s0] = cva;
    lossb[w] = lp;
  }
  __syncthreads();
  if (w == 0) {
    float p = (ln < 16) ? lossb[ln] : 0.f;
    p += __shfl_xor(p, 1); p += __shfl_xor(p, 2);
    p += __shfl_xor(p, 4); p += __shfl_xor(p, 8);
    if (ln == 0) atomicAdd(lacc, p);
  }
}

// ---------------- deferred ht = attn @ enc (fp32 VALU) + loss finalize -------
// grid 192: (b, tc of 8 t-rows(8), hc of 256 h-cols(3)). 256 threads.
__global__ __launch_bounds__(256) void ht_kernel(
    const float* __restrict__ attn, const float* __restrict__ enc,
    const float* __restrict__ dmask, const float* __restrict__ lacc,
    float* __restrict__ out_ht, float* __restrict__ out_loss)
{
  __shared__ float lat[Sq][8];     // [s][tt], 8 KB
  __shared__ float r4[4];
  int bid = blockIdx.x;
  int b = bid / 24, r = bid % 24, tc = r / 3, hc = r % 3;
  int tid = threadIdx.x;
  int h = hc * 256 + tid;
#pragma unroll
  for (int tt = 0; tt < 8; tt++)
    lat[tid][tt] = attn[(size_t)(b * Tq + tc * 8 + tt) * Sq + tid];
  __syncthreads();

  float acc[8] = {};
  const float* ep = enc + (size_t)(b * Sq) * Hq + h;
  for (int sb = 0; sb < Sq; sb += 8) {
    float e[8];
#pragma unroll
    for (int u = 0; u < 8; u++) e[u] = ep[(size_t)(sb + u) * Hq];
#pragma unroll
    for (int u = 0; u < 8; u++) {
      f32x4 a0 = *(const f32x4*)&lat[sb + u][0];
      f32x4 a1 = *(const f32x4*)&lat[sb + u][4];
      acc[0] += a0[0] * e[u]; acc[1] += a0[1] * e[u];
      acc[2] += a0[2] * e[u]; acc[3] += a0[3] * e[u];
      acc[4] += a1[0] * e[u]; acc[5] += a1[1] * e[u];
      acc[6] += a1[2] * e[u]; acc[7] += a1[3] * e[u];
    }
  }
#pragma unroll
  for (int tt = 0; tt < 8; tt++)
    out_ht[(size_t)(b * Tq + tc * 8 + tt) * Hq + h] = acc[tt];

  if (blockIdx.x == 0) {
    float s = 0.f;
    for (int i = tid; i < Bq * Tq; i += 256) s += dmask[i];
#pragma unroll
    for (int off = 32; off; off >>= 1) s += __shfl_xor(s, off);
    int w = tid >> 6, ln = tid & 63;
    if (ln == 0) r4[w] = s;
    __syncthreads();
    if (tid == 0) out_loss[0] = lacc[0] / (r4[0] + r4[1] + r4[2] + r4[3]);
  }
}

extern "C" void kernel_launch(void* const* d_in, const int* in_sizes, int n_in,
                              void* d_out, int out_size, void* d_ws, size_t ws_size,
                              hipStream_t stream) {
  const float* dec   = (const float*)d_in[0];   // [8,64,768]
  const float* dmask = (const float*)d_in[1];   // [8,64]
  const float* enc   = (const float*)d_in[2];   // [8,256,768]
  const float* emask = (const float*)d_in[3];   // [8,256]
  const float* cov0  = (const float*)d_in[4];   // [8,256]
  const float* Wh    = (const float*)d_in[5];   // [768,768]
  const float* Wd    = (const float*)d_in[6];   // [768,768]
  const float* bd    = (const float*)d_in[7];   // [768]
  const float* wc    = (const float*)d_in[8];   // [768]
  const float* vv    = (const float*)d_in[9];   // [768]
  float* out = (float*)d_out;

  char* ws = (char*)d_ws;
  float* ef   = (float*)ws;                           // 6291456 B
  float* decf = (float*)(ws + 6291456);               // 1572864 B
  unsigned long long* Zsync = (unsigned long long*)(ws + 7864320); // 32768 B
  float* lacc = (float*)(ws + 7897088);               // 4 B

  const size_t OFF_ATTN = (size_t)Bq * Tq * Hq;             // 393216
  const size_t OFF_LOSS = OFF_ATTN + (size_t)Bq * Tq * Sq;  // 524288
  const size_t OFF_COV  = OFF_LOSS + 1;                     // 524289

  proj_kernel<<<480, 256, 0, stream>>>(enc, dec, Wh, Wd, bd, ef, decf,
                                       Zsync, lacc);
  scan_kernel<<<Bq * GPB, 1024, 0, stream>>>(ef, decf, emask, cov0, vv, wc,
                                             dmask, out + OFF_ATTN,
                                             out + OFF_COV, Zsync, lacc);
  ht_kernel<<<192, 256, 0, stream>>>(out + OFF_ATTN, enc, dmask, lacc,
                                     out, out + OFF_LOSS);
}